// Round 1
// 165.649 us; speedup vs baseline: 1.0495x; 1.0495x over previous
//
#include <hip/hip_runtime.h>

// y = q_tok(x) @ q_grp(W)^T + bias, factored exactly:
//   q(x) = g_x * s_x[m], q(W) = g_w * s_w[n,grp] (grp=128 along K)
//   y[m,n] = s_x[m] * sum_grp s_w[n,grp] * (sum_{k in grp} g_x g_w)
// R6: operands packed as TRUE fp4 e2m1 nibbles (values are exactly the
// e2m1 grid): halves xq/wq/LDS traffic and uses the faster fp4 rate of
// mfma_scale_16x16x128_f8f6f4 (cbsz=blgp=4). GEMM moves to double-buffered
// LDS with counted vmcnt(4) (no per-step drain), raw s_barriers, setprio
// around the MFMA cluster, and per-block weight scales staged in LDS.

#define M_TOK 2048
#define N_OUT 4096
#define K_IN  4096
#define KB    2048    // packed fp4 bytes per K row (K_IN/2)
#define XBLK  2048    // x-role: one block per token row
#define WBLK  8192    // w-role: 2048 floats (16 groups) per block

typedef __attribute__((ext_vector_type(4))) int   int4v;
typedef __attribute__((ext_vector_type(8))) int   int8v;
typedef __attribute__((ext_vector_type(4))) float floatx4;

// fp4-e2m1 nibble via scale-premultiplied decision thresholds
// T = {.25,.75,1.25,1.75,2.5,3.5,5}*scale; codes 0..7 = {0,.5,1,1.5,2,3,4,6}
__device__ __forceinline__ unsigned int q_nib(
    float v, float t0, float t1, float t2, float t3, float t4, float t5, float t6)
{
    float a = fabsf(v);
    unsigned int m =
        a < t0 ? 0u : a < t1 ? 1u : a < t2 ? 2u : a < t3 ? 3u :
        a < t4 ? 4u : a < t5 ? 5u : a < t6 ? 6u : 7u;
    return m | ((__float_as_uint(v) >> 28) & 0x8u);
}

#define MK_THR(scale) \
    const float t0 = 0.25f * (scale), t1 = 0.75f * (scale), \
                t2 = 1.25f * (scale), t3 = 1.75f * (scale), \
                t4 = 2.5f  * (scale), t5 = 3.5f  * (scale), \
                t6 = 5.0f  * (scale);

__device__ __forceinline__ unsigned int pack8(
    const float* v, float t0, float t1, float t2, float t3,
    float t4, float t5, float t6)
{
    unsigned int u = 0;
    #pragma unroll
    for (int j = 0; j < 8; j++)
        u |= q_nib(v[j], t0, t1, t2, t3, t4, t5, t6) << (4 * j);
    return u;
}

// ---------- fused quant: blocks [0,XBLK) per-token x, rest per-group w ----------
__global__ __launch_bounds__(256) void quant_fused_kernel(
    const float* __restrict__ x, const float* __restrict__ w,
    unsigned char* __restrict__ xq, float* __restrict__ sx,
    unsigned char* __restrict__ wq, float* __restrict__ swt)
{
    const int t = threadIdx.x;
    const int lane = t & 63, wid = t >> 6;

    if (blockIdx.x < XBLK) {
        // ---- per-token row of 4096: clamp [-3,3], scale = absmax/6 ----
        const int row = blockIdx.x;
        const float* xr = x + (size_t)row * K_IN;
        float vals[16];
        float amax = 0.0f;
        #pragma unroll
        for (int i = 0; i < 2; i++) {
            const float* p = xr + i * 2048 + t * 8;   // 8 consecutive floats
            float4 a = *(const float4*)p;
            float4 b = *(const float4*)(p + 4);
            float tmp[8] = {a.x, a.y, a.z, a.w, b.x, b.y, b.z, b.w};
            #pragma unroll
            for (int j = 0; j < 8; j++) {
                float c = fminf(fmaxf(tmp[j], -3.0f), 3.0f);
                vals[i * 8 + j] = c;
                amax = fmaxf(amax, fabsf(c));
            }
        }
        #pragma unroll
        for (int off = 32; off; off >>= 1)
            amax = fmaxf(amax, __shfl_xor(amax, off));
        __shared__ float smax[4];
        if (lane == 0) smax[wid] = amax;
        __syncthreads();
        amax = fmaxf(fmaxf(smax[0], smax[1]), fmaxf(smax[2], smax[3]));

        const float scale = amax / 6.0f;
        if (t == 0) sx[row] = scale;
        MK_THR(scale);
        unsigned char* xo = xq + (size_t)row * KB;
        #pragma unroll
        for (int i = 0; i < 2; i++)
            *(unsigned int*)(xo + i * 1024 + t * 4) =
                pack8(&vals[i * 8], t0, t1, t2, t3, t4, t5, t6);
    } else {
        // ---- per-group w: block = 2048 floats = 16 groups; 16 lanes/group,
        //      8 consecutive elements per lane -> one packed uint ----
        const int b = blockIdx.x - XBLK;
        const float* base = w + (size_t)b * 2048 + t * 8;
        float4 v0 = *(const float4*)base;
        float4 v1 = *(const float4*)(base + 4);
        float vals[8] = {v0.x, v0.y, v0.z, v0.w, v1.x, v1.y, v1.z, v1.w};
        float amax = 0.0f;
        #pragma unroll
        for (int j = 0; j < 8; j++) amax = fmaxf(amax, fabsf(vals[j]));
        #pragma unroll
        for (int off = 8; off; off >>= 1)   // reduce within 16-lane cluster
            amax = fmaxf(amax, __shfl_xor(amax, off));
        const float scale = amax / 6.0f;
        const int G = b * 16 + (t >> 4);    // flat group id = n*32 + gk
        if ((lane & 15) == 0) swt[(size_t)(G & 31) * N_OUT + (G >> 5)] = scale;
        MK_THR(scale);
        *(unsigned int*)(wq + (size_t)b * 1024 + t * 4) =
            pack8(vals, t0, t1, t2, t3, t4, t5, t6);
    }
}

// ---------- async 16B global->LDS ----------
__device__ __forceinline__ void gld16(const unsigned char* g, unsigned char* l) {
    __builtin_amdgcn_global_load_lds(
        (const __attribute__((address_space(1))) void*)g,
        (__attribute__((address_space(3))) void*)l, 16, 0, 0);
}

// ---------- MX-fp4 GEMM, BK=128 = one quant group per MFMA ----------
// Double-buffered LDS, counted vmcnt (prefetch stays in flight across
// barriers), raw s_barrier, setprio(1) around the MFMA cluster.
__global__ __launch_bounds__(256) void gemm_mx4_kernel(
    const unsigned char* __restrict__ A, const float* __restrict__ sx,
    const unsigned char* __restrict__ B, const float* __restrict__ swt,
    const float* __restrict__ bias, float* __restrict__ C)
{
    __shared__ __align__(16) unsigned char As[2][128 * 64];  // 2 x 8 KB
    __shared__ __align__(16) unsigned char Bs[2][128 * 64];  // 2 x 8 KB
    __shared__ __align__(16) float svs[32][128];             // 16 KB scales

    const int tid = threadIdx.x;
    const int m0 = blockIdx.y * 128;
    const int n0 = blockIdx.x * 128;
    const int lane = tid & 63;
    const int wid  = tid >> 6;
    const int wm = (wid & 1) * 64;
    const int wn = (wid >> 1) * 64;
    const int lr = lane & 15;
    const int lq = lane >> 4;

    floatx4 mast[4][4] = {};

    // staging: 512 sub-chunks(16B) per buffer, 2/thread each for A and B;
    // rotation swizzle phys=(c+row)&3 (inverse applied on the global source
    // so the LDS dest stays wave-uniform + lane*16)
    const unsigned char* gA[2];
    const unsigned char* gB[2];
    int ldst[2];
    #pragma unroll
    for (int i = 0; i < 2; i++) {
        const int P = tid + i * 256;
        const int row = P >> 2, ph = P & 3;
        const int c = (ph - row) & 3;
        gA[i] = A + (size_t)(m0 + row) * KB + c * 16;
        gB[i] = B + (size_t)(n0 + row) * KB + c * 16;
        ldst[i] = P * 16;
    }

    // one-time stage of this block's weight scales: swt[g][n0..n0+128)
    #pragma unroll
    for (int i = 0; i < 4; i++) {
        const int flat = tid + i * 256;          // float4 index, 1024 total
        const int g = flat >> 5, c = (flat & 31) << 2;
        *(float4*)&svs[g][c] = *(const float4*)(swt + (size_t)g * N_OUT + n0 + c);
    }

    // prologue: stage k-group 0 into buffer 0
    #pragma unroll
    for (int i = 0; i < 2; i++) {
        gld16(gA[i], &As[0][ldst[i]]);
        gld16(gB[i], &Bs[0][ldst[i]]);
    }
    __syncthreads();   // drains prologue loads + svs writes, once

    const floatx4 zero = {0.0f, 0.0f, 0.0f, 0.0f};

    for (int g = 0; g < 32; g++) {
        const int cur = g & 1;
        if (g < 31) {
            // issue next tile's 4 loads into the other buffer; keep them in
            // flight -- wait only for the 4 older loads (current buffer)
            const int koff = (g + 1) * 64;
            #pragma unroll
            for (int i = 0; i < 2; i++) {
                gld16(gA[i] + koff, &As[cur ^ 1][ldst[i]]);
                gld16(gB[i] + koff, &Bs[cur ^ 1][ldst[i]]);
            }
            asm volatile("s_waitcnt vmcnt(4)" ::: "memory");
        } else {
            asm volatile("s_waitcnt vmcnt(0)" ::: "memory");
        }
        __builtin_amdgcn_s_barrier();            // buf[cur] ready for all
        __builtin_amdgcn_sched_barrier(0);

        float sv[4];
        #pragma unroll
        for (int ni = 0; ni < 4; ni++)
            sv[ni] = svs[g][wn + ni * 16 + lr];

        // fragment reads: fp4 => one 16B chunk per fragment (32 elems/lane)
        int8v af[4], bf[4];
        #pragma unroll
        for (int mi = 0; mi < 4; mi++) {
            const int row = wm + mi * 16 + lr;
            const int slot = (lq + row) & 3;
            int4v d = *(const int4v*)&As[cur][row * 64 + slot * 16];
            af[mi] = (int8v){d[0], d[1], d[2], d[3], 0, 0, 0, 0};
        }
        #pragma unroll
        for (int ni = 0; ni < 4; ni++) {
            const int row = wn + ni * 16 + lr;
            const int slot = (lq + row) & 3;
            int4v d = *(const int4v*)&Bs[cur][row * 64 + slot * 16];
            bf[ni] = (int8v){d[0], d[1], d[2], d[3], 0, 0, 0, 0};
        }
        asm volatile("s_waitcnt lgkmcnt(0)" ::: "memory");
        __builtin_amdgcn_sched_barrier(0);       // rule #18: pin MFMA below
        __builtin_amdgcn_s_barrier();            // buf[cur] free for overwrite

        __builtin_amdgcn_s_setprio(1);
        #pragma unroll
        for (int mi = 0; mi < 4; mi++)
            #pragma unroll
            for (int ni = 0; ni < 4; ni++) {
                floatx4 tacc = __builtin_amdgcn_mfma_scale_f32_16x16x128_f8f6f4(
                    af[mi], bf[ni], zero, 4, 4,          // cbsz=blgp=4 -> fp4
                    0, 0x7F7F7F7F, 0, 0x7F7F7F7F);       // e8m0 scales = 1.0
                mast[mi][ni] += sv[ni] * tacc;
            }
        __builtin_amdgcn_s_setprio(0);
    }

    // epilogue: C/D layout col=lane&15, row=(lane>>4)*4+reg [m89/m91]
    #pragma unroll
    for (int mi = 0; mi < 4; mi++) {
        const int rbase = m0 + wm + mi * 16 + lq * 4;
        #pragma unroll
        for (int ni = 0; ni < 4; ni++) {
            const int cc = n0 + wn + ni * 16 + lr;
            const float bb = bias[cc];
            #pragma unroll
            for (int r = 0; r < 4; r++)
                C[(size_t)(rbase + r) * N_OUT + cc] =
                    sx[rbase + r] * mast[mi][ni][r] + bb;
        }
    }
}

extern "C" void kernel_launch(void* const* d_in, const int* in_sizes, int n_in,
                              void* d_out, int out_size, void* d_ws, size_t ws_size,
                              hipStream_t stream) {
    const float* x    = (const float*)d_in[0];
    const float* w    = (const float*)d_in[1];
    const float* bias = (const float*)d_in[2];
    float* out = (float*)d_out;

    unsigned char* xq = (unsigned char*)d_ws;                       // 4 MB
    unsigned char* wq = xq + (size_t)M_TOK * KB;                    // 8 MB
    float* swt = (float*)(wq + (size_t)N_OUT * KB);                 // 512 KB, [32][4096]
    float* sx  = swt + (size_t)(K_IN / 128) * N_OUT;                // 8 KB

    quant_fused_kernel<<<XBLK + WBLK, 256, 0, stream>>>(x, w, xq, sx, wq, swt);
    gemm_mx4_kernel<<<dim3(N_OUT / 128, M_TOK / 128), 256, 0, stream>>>(
        xq, sx, wq, swt, bias, out);
}